// Round 10
// baseline (117.539 us; speedup 1.0000x reference)
//
#include <hip/hip_runtime.h>
#include <hip/hip_bf16.h>

typedef __attribute__((ext_vector_type(8))) short short8;
typedef __attribute__((ext_vector_type(4))) float floatx4;

#define NROWS 4096
#define NHALF 2048
#define DDIM  128
#define SQRT_SCALE 2.6857914f     // sqrt(1/(0.2*ln2)) ; dot of stored z == (sim/T)*log2(e)
#define LN2 0.69314718056f

// ws float layout: [0]=loss acc, [1]=all_num, [2]=k_loss completion counter,
// part [64, 64+4*32*4096) : part[l][k][n] = sum_{m in col-tile k} exp2(z_n . z_m)
//   slot k = column-tile index; for row n (row-tile R=n>>7): k>=R written by block (R,k)
//   row-side, k<R written by block (k,R) col-side -> EXACTLY ONE writer per element,
//   plain stores, no zero-init, no atomics.
#define WS_PART_OFF 64
#define WS_DIAG_OFF 524352        // 64 + 4*32*4096
#define WS_POS_OFF  540736        // + 16384
#define WS_Z_BYTE_OFF 2228480     // (WS_POS_OFF + 16384)*4, 16B aligned

__device__ inline unsigned short f2bf(float f) {
    unsigned u = __builtin_bit_cast(unsigned, f);
    u += 0x7fffu + ((u >> 16) & 1u);          // RNE
    return (unsigned short)(u >> 16);
}

__device__ inline void tilecoords(int idx, int& I, int& J) {
    int j = (int)((sqrtf(8.f * (float)idx + 1.f) - 1.f) * 0.5f);
    while ((j + 1) * (j + 2) / 2 <= idx) ++j; // guard fp rounding
    while (j * (j + 1) / 2 > idx) --j;
    J = j; I = idx - j * (j + 1) / 2;
}

// ---------------- kernel 1: normalize + scale + cast to bf16; zero scalars; all_num --------
__global__ __launch_bounds__(256) void k_norm(const float* __restrict__ emb_i,
                                              const float* __restrict__ emb_j,
                                              const float* __restrict__ jv,
                                              float* __restrict__ wsf,
                                              unsigned short* __restrict__ z) {
    int bx = blockIdx.x, tid = threadIdx.x;
    if (bx == 4096) {                         // all_num = sum(joint_valid)
        __shared__ float sred[256];
        float s = 0.f;
        #pragma unroll
        for (int i = 0; i < 8; ++i) s += jv[tid + 256 * i];
        sred[tid] = s; __syncthreads();
        for (int off = 128; off > 0; off >>= 1) {
            if (tid < off) sred[tid] += sred[tid + off];
            __syncthreads();
        }
        if (tid == 0) wsf[1] = sred[0];
        return;
    }
    if (bx == 0 && tid == 0) { wsf[0] = 0.f; *(unsigned*)&wsf[2] = 0u; }

    int wave = tid >> 6, lane = tid & 63;
    int r = bx * 4 + wave;                    // global row 0..16383
    int l = r >> 12, n = r & 4095;
    const float* src = (n < NHALF) ? (emb_i + ((size_t)l * NHALF + n) * DDIM)
                                   : (emb_j + ((size_t)l * NHALF + (n - NHALF)) * DDIM);
    float2 v = *(const float2*)(src + lane * 2);
    float ss = v.x * v.x + v.y * v.y;
    #pragma unroll
    for (int off = 1; off < 64; off <<= 1) ss += __shfl_xor(ss, off);
    float inv = SQRT_SCALE / fmaxf(sqrtf(ss), 1e-12f);
    unsigned pack = ((unsigned)f2bf(v.y * inv) << 16) | (unsigned)f2bf(v.x * inv);
    *(unsigned*)(z + (size_t)r * DDIM + lane * 2) = pack;
}

// ---------------- kernel 2: BARRIER-FREE symmetric sim GEMM + exp2 sums --------------------
// R9 post-mortem: register-held prefetch spilled (VGPR 100 alloc vs ~156 live, 67MB
// scratch writes) -> persistent+reg-prefetch is dead (0-for-2 with R5). But R9 gave the
// first clean k_sim profile since R2: MfmaUtil 6.5, VALUBusy 13.5, HBM 21, Occ 15 -> ALL
// pipes idle; ~60% of cycles are waves stalled on the stage->barrier->ds_read->MFMA
// coupling (all 4 waves stall together).
// R10 (single-variable edit on R6, the best-measured family): DELETE LDS staging. B-tile
// is L2-resident (z slice 1MB/XCD via bx&3=l); each wave reads B short8-fragments direct
// from L2. Costs ~4x L2 traffic on B (~270MB total ~ 8us device-wide, less with L1 hits
// since all 4 waves read the same rows); buys ZERO barriers and ZERO LDS deps in the tile
// loop -> pure load->MFMA dataflow the compiler pipelines across cs, and waves/blocks
// stall-fill each other. LDS drops 34KB -> 2KB (cred only, one barrier per block).
// Uncapped launch bounds: every cap attempt spilled (R1/R5/R8/R9) or was neutral (R4).
__global__ __launch_bounds__(256) void k_sim(const unsigned short* __restrict__ z,
                                             float* __restrict__ part,
                                             float* __restrict__ diag,
                                             float* __restrict__ pos) {
    __shared__ float cred[4][128];
    int bx = blockIdx.x, tid = threadIdx.x;
    int l = bx & 3, idx = bx >> 2;            // idx in [0,528)
    int I, J;
    tilecoords(idx, I, J);
    int wave = tid >> 6, lane = tid & 63, m = lane & 15, quad = lane >> 4;
    const unsigned short* zl = z + (size_t)l * NROWS * DDIM;
    int l4 = l * NROWS;
    int wr0 = I * 128 + wave * 32;            // 32 rows per wave
    int cg0 = J * 128;

    short8 a[2][4];                           // 2 row-subtiles x 4 k-steps
    #pragma unroll
    for (int rs = 0; rs < 2; ++rs) {
        const unsigned short* pa = zl + (size_t)(wr0 + rs * 16 + m) * DDIM + quad * 8;
        #pragma unroll
        for (int kk = 0; kk < 4; ++kk) a[rs][kk] = *(const short8*)(pa + kk * 32);
    }
    floatx4 rsum[2];
    rsum[0] = (floatx4){0.f, 0.f, 0.f, 0.f};
    rsum[1] = (floatx4){0.f, 0.f, 0.f, 0.f};
    float csum[8];                            // per-lane col partial, col = cs*16 + m
    #pragma unroll
    for (int g = 0; g < 8; ++g) csum[g] = 0.f;

    const unsigned short* pb = zl + (size_t)(cg0 + m) * DDIM + quad * 8;
    #pragma unroll
    for (int cs = 0; cs < 8; ++cs) {          // 16-col subtiles, B direct from L2
        int ct = cg0 + cs * 16;               // tile column base (wave-uniform)
        const unsigned short* lp = pb + (size_t)cs * 16 * DDIM;
        short8 b0 = *(const short8*)(lp);
        short8 b1 = *(const short8*)(lp + 32);
        short8 b2 = *(const short8*)(lp + 64);
        short8 b3 = *(const short8*)(lp + 96);
        #pragma unroll
        for (int rs = 0; rs < 2; ++rs) {
            floatx4 acc = (floatx4){0.f, 0.f, 0.f, 0.f};
            acc = __builtin_amdgcn_mfma_f32_16x16x32_bf16(a[rs][0], b0, acc, 0, 0, 0);
            acc = __builtin_amdgcn_mfma_f32_16x16x32_bf16(a[rs][1], b1, acc, 0, 0, 0);
            acc = __builtin_amdgcn_mfma_f32_16x16x32_bf16(a[rs][2], b2, acc, 0, 0, 0);
            acc = __builtin_amdgcn_mfma_f32_16x16x32_bf16(a[rs][3], b3, acc, 0, 0, 0);
            int rowbase = wr0 + rs * 16;
            bool isdiag = (ct == rowbase);          // only when I==J
            bool ispos  = (ct == rowbase + 2048);   // only when J==I+16
            if (isdiag || ispos) {            // rare, wave-uniform branch
                int c = m - (quad << 2);      // acc[c] holds sim[rowbase+quad*4+c][ct+m]
                if (c >= 0 && c < 4) {        // -> diagonal element iff quad*4+c == m
                    float v = acc[c];
                    if (isdiag) diag[l4 + rowbase + m] = v;
                    else {                    // sim[r, r+2048]; pos symmetric across halves
                        pos[l4 + rowbase + m] = v;
                        pos[l4 + rowbase + m + NHALF] = v;
                    }
                }
            }
            float t = 0.f;
            #pragma unroll
            for (int c = 0; c < 4; ++c) {
                float e = __builtin_amdgcn_exp2f(acc[c]);
                rsum[rs][c] += e;
                t += e;                       // sum over this lane's 4 rows
            }
            csum[cs] += t;                    // accumulate col partial across rs
        }
    }
    // row side: reduce across the 16 column-lanes; plain stores to slot J (unique writer)
    #pragma unroll
    for (int off = 1; off < 16; off <<= 1)
        #pragma unroll
        for (int rs = 0; rs < 2; ++rs)
            #pragma unroll
            for (int c = 0; c < 4; ++c)
                rsum[rs][c] += __shfl_xor(rsum[rs][c], off);
    float* plJ = part + (size_t)(l * 32 + J) * 4096;
    if (m == 0) {                             // lanes 0,16,32,48: rows wr0 + rs*16 + quad*4 + c
        #pragma unroll
        for (int rs = 0; rs < 2; ++rs)
            #pragma unroll
            for (int c = 0; c < 4; ++c)
                plJ[wr0 + rs * 16 + quad * 4 + c] = rsum[rs][c];
    }
    // col side (transpose contribution) -> slot I, off-diagonal tiles only
    if (I != J) {
        #pragma unroll
        for (int g = 0; g < 8; ++g) {         // finish reduce over the 16 rows (lane bits 4,5)
            float v = csum[g];
            v += __shfl_xor(v, 16);
            v += __shfl_xor(v, 32);
            if (quad == 0) cred[wave][g * 16 + m] = v;
        }
        __syncthreads();                      // only barrier in the kernel
        if (tid < 128) {
            float s = cred[0][tid] + cred[1][tid] + cred[2][tid] + cred[3][tid];
            part[(size_t)(l * 32 + I) * 4096 + cg0 + tid] = s;  // plain store (unique writer)
        }
    }
}

// ---------------- kernel 3: gather 32 partials/row -> loss; last block finalizes -----------
__global__ __launch_bounds__(256) void k_loss(const float* __restrict__ jv,
                                              const float* __restrict__ part,
                                              const float* __restrict__ diag,
                                              const float* __restrict__ pos,
                                              float* __restrict__ wsf,
                                              float* __restrict__ out) {
    __shared__ float sred[256];
    int tid = threadIdx.x;
    int r = blockIdx.x * 256 + tid;           // 64 blocks x 256 = 16384 rows
    int l = r >> 12, n = r & 4095;
    const float* pl = part + (size_t)l * 32 * 4096 + n;
    float s = 0.f;
    #pragma unroll
    for (int k = 0; k < 32; ++k) s += pl[(size_t)k * 4096];   // coalesced across lanes
    float denom = s - __builtin_amdgcn_exp2f(diag[r]);
    float contrib = LN2 * (__builtin_amdgcn_logf(denom) - pos[r]); // logf = v_log_f32 = log2
    float local = contrib * jv[n & (NHALF - 1)];
    sred[tid] = local; __syncthreads();
    for (int off = 128; off > 0; off >>= 1) {
        if (tid < off) sred[tid] += sred[tid + off];
        __syncthreads();
    }
    if (tid == 0) {
        atomicAdd(&wsf[0], sred[0]);
        __threadfence();                      // order loss-add before counter-add
        unsigned c = atomicAdd((unsigned*)&wsf[2], 1u);
        if (c == 63) {                        // 64th (last) block: finalize
            float tot = atomicAdd(&wsf[0], 0.f);   // device-scope coherent read
            out[0] = tot / (2.f * wsf[1]);
        }
    }
}

extern "C" void kernel_launch(void* const* d_in, const int* in_sizes, int n_in,
                              void* d_out, int out_size, void* d_ws, size_t ws_size,
                              hipStream_t stream) {
    const float* emb_i = (const float*)d_in[0];
    const float* emb_j = (const float*)d_in[1];
    const float* jv    = (const float*)d_in[2];
    float* wsf  = (float*)d_ws;
    float* part = wsf + WS_PART_OFF;
    float* diag = wsf + WS_DIAG_OFF;
    float* pos  = wsf + WS_POS_OFF;
    unsigned short* z = (unsigned short*)((char*)d_ws + WS_Z_BYTE_OFF);
    float* out = (float*)d_out;

    k_norm <<<4097, 256, 0, stream>>>(emb_i, emb_j, jv, wsf, z);
    k_sim  <<<2112, 256, 0, stream>>>(z, part, diag, pos);   // 4 l x 528 upper-tri 128x128
    k_loss <<<64,   256, 0, stream>>>(jv, part, diag, pos, wsf, out);
}

// Round 11
// 98.927 us; speedup vs baseline: 1.1881x; 1.1881x over previous
//
#include <hip/hip_runtime.h>
#include <hip/hip_bf16.h>

typedef __attribute__((ext_vector_type(8))) short short8;
typedef __attribute__((ext_vector_type(4))) float floatx4;

#define NROWS 4096
#define NHALF 2048
#define DDIM  128
#define LDST  136                 // LDS row stride in ushorts (128 + 8 pad -> 272B, 2-way = free)
#define SQRT_SCALE 2.6857914f     // sqrt(1/(0.2*ln2)) ; dot of stored z == (sim/T)*log2(e)
#define LN2 0.69314718056f

// ws float layout: [0]=loss acc, [1]=all_num, [2]=k_loss completion counter,
// part [64, 64+4*32*4096) : part[l][k][n] = sum_{m in col-tile k} exp2(z_n . z_m)
//   slot k = 128-col-tile index; for row n (row-tile R=n>>7): k>=R written by the block
//   owning row-tile R at col-stage k (row-side), k<R by the block owning row-tile k at
//   col-stage covering n (col-side) -> EXACTLY ONE writer per element, plain stores.
#define WS_PART_OFF 64
#define WS_DIAG_OFF 524352        // 64 + 4*32*4096
#define WS_POS_OFF  540736        // + 16384
#define WS_Z_BYTE_OFF 2228480     // (WS_POS_OFF + 16384)*4, 16B aligned

__device__ inline unsigned short f2bf(float f) {
    unsigned u = __builtin_bit_cast(unsigned, f);
    u += 0x7fffu + ((u >> 16) & 1u);          // RNE
    return (unsigned short)(u >> 16);
}

// ---------------- kernel 1: normalize + scale + cast to bf16; zero scalars; all_num --------
__global__ __launch_bounds__(256) void k_norm(const float* __restrict__ emb_i,
                                              const float* __restrict__ emb_j,
                                              const float* __restrict__ jv,
                                              float* __restrict__ wsf,
                                              unsigned short* __restrict__ z) {
    int bx = blockIdx.x, tid = threadIdx.x;
    if (bx == 4096) {                         // all_num = sum(joint_valid)
        __shared__ float sred[256];
        float s = 0.f;
        #pragma unroll
        for (int i = 0; i < 8; ++i) s += jv[tid + 256 * i];
        sred[tid] = s; __syncthreads();
        for (int off = 128; off > 0; off >>= 1) {
            if (tid < off) sred[tid] += sred[tid + off];
            __syncthreads();
        }
        if (tid == 0) wsf[1] = sred[0];
        return;
    }
    if (bx == 0 && tid == 0) { wsf[0] = 0.f; *(unsigned*)&wsf[2] = 0u; }

    int wave = tid >> 6, lane = tid & 63;
    int r = bx * 4 + wave;                    // global row 0..16383
    int l = r >> 12, n = r & 4095;
    const float* src = (n < NHALF) ? (emb_i + ((size_t)l * NHALF + n) * DDIM)
                                   : (emb_j + ((size_t)l * NHALF + (n - NHALF)) * DDIM);
    float2 v = *(const float2*)(src + lane * 2);
    float ss = v.x * v.x + v.y * v.y;
    #pragma unroll
    for (int off = 1; off < 64; off <<= 1) ss += __shfl_xor(ss, off);
    float inv = SQRT_SCALE / fmaxf(sqrtf(ss), 1e-12f);
    unsigned pack = ((unsigned)f2bf(v.y * inv) << 16) | (unsigned)f2bf(v.x * inv);
    *(unsigned*)(z + (size_t)r * DDIM + lane * 2) = pack;
}

// ---------------- kernel 2: COLUMN-STAGED fat-block symmetric sim + exp2 sums --------------
// R10 post-mortem: direct-L2 B reads regressed (49.7us, per-iteration L2 latency exposed)
// -> LDS staging vindicated. Quantitative model from R2/R9/R10 profiles: inner loop is
// ~40 VALU-cyc per 5-cyc MFMA (4 exp2 + 8 adds) -> ~9-10.5us/SIMD irreducible VALU for
// the symmetric half; R6 = 21us is ~50% VALU-busy, R0's fat 4-stage blocks were ~90% on
// 2x work. Gap = R6's per-block overheads (a-loads, launch/drain, tails) paid per single
// 128^2 stage-unit. R11 = R0's structure at symmetric work: blocks of 128 rows x <=512
// cols; per block, col-stages k in [max(rb,4cb), 4cb+3] staged sequentially into ONE 34KB
// LDS buffer; per-stage mode: k==rb -> diag (rowsum only), k>rb -> full (row+col sums).
// a-frags loaded once per block (amortized 4x). Same 528 stage-units/l; 576 blocks
// (1.125 rounds at 2/CU). Emission code identical to R6 with J -> k. Uncapped VGPR
// (every cap spilled: R1/R5/R9; R4 cap was neutral).
__global__ __launch_bounds__(256) void k_sim(const unsigned short* __restrict__ z,
                                             float* __restrict__ part,
                                             float* __restrict__ diag,
                                             float* __restrict__ pos) {
    __shared__ __align__(16) unsigned short lds[128 * LDST];
    __shared__ float cred[4][128];
    int bx = blockIdx.x, tid = threadIdx.x;
    int l = bx & 3, t = bx >> 2;              // t in [0,144): tiles (rb,cb), rb <= 4cb+3
    int cb = 0, cum = 0;
    while (cb < 7) {                          // decode: n(cb) = min(32, 4cb+4) blocks per cb
        int n = 4 * cb + 4; if (n > 32) n = 32;
        if (cum + n > t) break;
        cum += n; ++cb;
    }
    int rb = t - cum;                         // row-tile 0..31 (128 rows)
    int k0 = rb > 4 * cb ? rb : 4 * cb;       // first col-stage
    int k1 = 4 * cb + 3;                      // last col-stage

    int wave = tid >> 6, lane = tid & 63, m = lane & 15, quad = lane >> 4;
    const unsigned short* zl = z + (size_t)l * NROWS * DDIM;
    int l4 = l * NROWS;
    int wr0 = rb * 128 + wave * 32;           // 32 rows per wave

    short8 a[2][4];                           // 2 row-subtiles x 4 k-steps, loaded ONCE
    #pragma unroll
    for (int rs = 0; rs < 2; ++rs) {
        const unsigned short* pa = zl + (size_t)(wr0 + rs * 16 + m) * DDIM + quad * 8;
        #pragma unroll
        for (int kk = 0; kk < 4; ++kk) a[rs][kk] = *(const short8*)(pa + kk * 32);
    }

    // stage first col-tile k0
    #pragma unroll
    for (int i = 0; i < 8; ++i) {
        int chunk = tid + 256 * i;
        int col = chunk >> 4, off = chunk & 15;
        uint4 d = *(const uint4*)(zl + (size_t)(k0 * 128 + col) * DDIM + off * 8);
        *(uint4*)&lds[col * LDST + off * 8] = d;
    }
    __syncthreads();

    for (int k = k0; k <= k1; ++k) {
        int cg0 = k * 128;
        floatx4 rsum[2];
        rsum[0] = (floatx4){0.f, 0.f, 0.f, 0.f};
        rsum[1] = (floatx4){0.f, 0.f, 0.f, 0.f};
        float csum[8];
        #pragma unroll
        for (int g = 0; g < 8; ++g) csum[g] = 0.f;

        #pragma unroll
        for (int cs = 0; cs < 8; ++cs) {      // 16-col subtiles
            int ct = cg0 + cs * 16;           // subtile column base (wave-uniform)
            const unsigned short* lp = &lds[(cs * 16 + m) * LDST + quad * 8];
            short8 b0 = *(const short8*)(lp);
            short8 b1 = *(const short8*)(lp + 32);
            short8 b2 = *(const short8*)(lp + 64);
            short8 b3 = *(const short8*)(lp + 96);
            #pragma unroll
            for (int rs = 0; rs < 2; ++rs) {
                floatx4 acc = (floatx4){0.f, 0.f, 0.f, 0.f};
                acc = __builtin_amdgcn_mfma_f32_16x16x32_bf16(a[rs][0], b0, acc, 0, 0, 0);
                acc = __builtin_amdgcn_mfma_f32_16x16x32_bf16(a[rs][1], b1, acc, 0, 0, 0);
                acc = __builtin_amdgcn_mfma_f32_16x16x32_bf16(a[rs][2], b2, acc, 0, 0, 0);
                acc = __builtin_amdgcn_mfma_f32_16x16x32_bf16(a[rs][3], b3, acc, 0, 0, 0);
                int rowbase = wr0 + rs * 16;
                bool isdiag = (ct == rowbase);          // only when k==rb, cs==wave*2+rs
                bool ispos  = (ct == rowbase + 2048);   // only when k==rb+16
                if (isdiag || ispos) {        // rare, wave-uniform branch
                    int c = m - (quad << 2);  // acc[c] holds sim[rowbase+quad*4+c][ct+m]
                    if (c >= 0 && c < 4) {    // -> diagonal element iff quad*4+c == m
                        float v = acc[c];
                        if (isdiag) diag[l4 + rowbase + m] = v;
                        else {                // sim[r, r+2048]; pos symmetric across halves
                            pos[l4 + rowbase + m] = v;
                            pos[l4 + rowbase + m + NHALF] = v;
                        }
                    }
                }
                float tsum = 0.f;
                #pragma unroll
                for (int c = 0; c < 4; ++c) {
                    float e = __builtin_amdgcn_exp2f(acc[c]);
                    rsum[rs][c] += e;
                    tsum += e;                // sum over this lane's 4 rows
                }
                csum[cs] += tsum;             // accumulate col partial across rs
            }
        }
        // row side: reduce across the 16 column-lanes; plain stores to slot k
        #pragma unroll
        for (int off = 1; off < 16; off <<= 1)
            #pragma unroll
            for (int rs = 0; rs < 2; ++rs)
                #pragma unroll
                for (int c = 0; c < 4; ++c)
                    rsum[rs][c] += __shfl_xor(rsum[rs][c], off);
        float* plK = part + (size_t)(l * 32 + k) * 4096;
        if (m == 0) {                         // lanes 0,16,32,48: rows wr0 + rs*16 + quad*4 + c
            #pragma unroll
            for (int rs = 0; rs < 2; ++rs)
                #pragma unroll
                for (int c = 0; c < 4; ++c)
                    plK[wr0 + rs * 16 + quad * 4 + c] = rsum[rs][c];
        }
        // col side partials -> cred (full-mode stages only; k,rb block-uniform)
        if (k != rb) {
            #pragma unroll
            for (int g = 0; g < 8; ++g) {     // finish reduce over 16 rows (lane bits 4,5)
                float v = csum[g];
                v += __shfl_xor(v, 16);
                v += __shfl_xor(v, 32);
                if (quad == 0) cred[wave][g * 16 + m] = v;
            }
        }
        __syncthreads();                      // compute ds_reads + cred writes complete
        if (k < k1) {                         // stage next col-tile into the same buffer
            #pragma unroll
            for (int i = 0; i < 8; ++i) {
                int chunk = tid + 256 * i;
                int col = chunk >> 4, off = chunk & 15;
                uint4 d = *(const uint4*)(zl + (size_t)((k + 1) * 128 + col) * DDIM + off * 8);
                *(uint4*)&lds[col * LDST + off * 8] = d;
            }
        }
        if (k != rb && tid < 128) {           // col-side store (unique writer, slot rb)
            float s = cred[0][tid] + cred[1][tid] + cred[2][tid] + cred[3][tid];
            part[(size_t)(l * 32 + rb) * 4096 + cg0 + tid] = s;
        }
        __syncthreads();                      // B staged + cred consumed before next write
    }
}

// ---------------- kernel 3: gather 32 partials/row -> loss; last block finalizes -----------
__global__ __launch_bounds__(256) void k_loss(const float* __restrict__ jv,
                                              const float* __restrict__ part,
                                              const float* __restrict__ diag,
                                              const float* __restrict__ pos,
                                              float* __restrict__ wsf,
                                              float* __restrict__ out) {
    __shared__ float sred[256];
    int tid = threadIdx.x;
    int r = blockIdx.x * 256 + tid;           // 64 blocks x 256 = 16384 rows
    int l = r >> 12, n = r & 4095;
    const float* pl = part + (size_t)l * 32 * 4096 + n;
    float s = 0.f;
    #pragma unroll
    for (int k = 0; k < 32; ++k) s += pl[(size_t)k * 4096];   // coalesced across lanes
    float denom = s - __builtin_amdgcn_exp2f(diag[r]);
    float contrib = LN2 * (__builtin_amdgcn_logf(denom) - pos[r]); // logf = v_log_f32 = log2
    float local = contrib * jv[n & (NHALF - 1)];
    sred[tid] = local; __syncthreads();
    for (int off = 128; off > 0; off >>= 1) {
        if (tid < off) sred[tid] += sred[tid + off];
        __syncthreads();
    }
    if (tid == 0) {
        atomicAdd(&wsf[0], sred[0]);
        __threadfence();                      // order loss-add before counter-add
        unsigned c = atomicAdd((unsigned*)&wsf[2], 1u);
        if (c == 63) {                        // 64th (last) block: finalize
            float tot = atomicAdd(&wsf[0], 0.f);   // device-scope coherent read
            out[0] = tot / (2.f * wsf[1]);
        }
    }
}

extern "C" void kernel_launch(void* const* d_in, const int* in_sizes, int n_in,
                              void* d_out, int out_size, void* d_ws, size_t ws_size,
                              hipStream_t stream) {
    const float* emb_i = (const float*)d_in[0];
    const float* emb_j = (const float*)d_in[1];
    const float* jv    = (const float*)d_in[2];
    float* wsf  = (float*)d_ws;
    float* part = wsf + WS_PART_OFF;
    float* diag = wsf + WS_DIAG_OFF;
    float* pos  = wsf + WS_POS_OFF;
    unsigned short* z = (unsigned short*)((char*)d_ws + WS_Z_BYTE_OFF);
    float* out = (float*)d_out;

    k_norm <<<4097, 256, 0, stream>>>(emb_i, emb_j, jv, wsf, z);
    k_sim  <<<576,  256, 0, stream>>>(z, part, diag, pos);   // 4 l x 144 fat tiles
    k_loss <<<64,   256, 0, stream>>>(jv, part, diag, pos, wsf, out);
}

// Round 13
// 88.924 us; speedup vs baseline: 1.3218x; 1.1125x over previous
//
#include <hip/hip_runtime.h>
#include <hip/hip_bf16.h>

typedef __attribute__((ext_vector_type(8))) short short8;
typedef __attribute__((ext_vector_type(4))) float floatx4;

#define NROWS 4096
#define NHALF 2048
#define DDIM  128
#define LDST  136                 // LDS row stride in ushorts (128 + 8 pad -> 272B, 2-way = free)
#define SQRT_SCALE 2.6857914f     // sqrt(1/(0.2*ln2)) ; dot of stored z == (sim/T)*log2(e)
#define LN2 0.69314718056f

// ws float layout: [0]=loss acc, [1]=all_num, [2]=k_loss completion counter,
// rowsum [64, 64+16384), diag [16448, +16384), pos [32832, +16384)
#define WS_ROWSUM_OFF 64
#define WS_DIAG_OFF   16448
#define WS_POS_OFF    32832
#define WS_Z_BYTE_OFF 196864      // (64+3*16384)*4, 16B aligned

// SESSION LEDGER (R0-R12): best = THIS kernel (R3, 87.6us; R4 +cap 88.0; R6 part-store
// 89.3 — tied within the +/-3us cross-round noise of the harness poison fills, which
// vary 40.6-44.5us each). Failed to beat it: tile-pairing (R5, VGPR pressure),
// persistent+reg-prefetch (R9, allocator spills prefetch state: VGPR 100/67MB scratch),
// LDS-free direct-L2 B (R10, per-iter L2 latency exposed: 49.7us), fat col-staged blocks
// (R11, variable-length block packing tail: 98.9). Neutral: occupancy cap (R4),
// atomic->unique-writer stores (R6). R12: container failed twice on THIS exact proven
// binary -> infra flake confirmed (also de-implicates R7/R8 kernels). Floor analysis:
// timed region = 2 x 256MiB harness workspace-poison fills at ~80% HBM peak (~83-84us,
// unremovable from kernel_launch) + ~4-5us kernel tail. Headroom <= ~5%, below noise.
__device__ inline unsigned short f2bf(float f) {
    unsigned u = __builtin_bit_cast(unsigned, f);
    u += 0x7fffu + ((u >> 16) & 1u);          // RNE
    return (unsigned short)(u >> 16);
}

// ---------------- kernel 1: normalize + scale + cast to bf16; zero accumulators; all_num ----
__global__ __launch_bounds__(256) void k_norm(const float* __restrict__ emb_i,
                                              const float* __restrict__ emb_j,
                                              const float* __restrict__ jv,
                                              float* __restrict__ wsf,
                                              unsigned short* __restrict__ z) {
    int bx = blockIdx.x, tid = threadIdx.x;
    if (bx == 4096) {                         // all_num = sum(joint_valid)
        __shared__ float sred[256];
        float s = 0.f;
        #pragma unroll
        for (int i = 0; i < 8; ++i) s += jv[tid + 256 * i];
        sred[tid] = s; __syncthreads();
        for (int off = 128; off > 0; off >>= 1) {
            if (tid < off) sred[tid] += sred[tid + off];
            __syncthreads();
        }
        if (tid == 0) wsf[1] = sred[0];
        return;
    }
    int gid = bx * 256 + tid;                 // zero loss acc + counter + rowsum (ws poisoned each call)
    if (gid == 0) { wsf[0] = 0.f; *(unsigned*)&wsf[2] = 0u; }
    if (gid >= WS_ROWSUM_OFF && gid < WS_ROWSUM_OFF + 16384) wsf[gid] = 0.f;

    int wave = tid >> 6, lane = tid & 63;
    int r = bx * 4 + wave;                    // global row 0..16383
    int l = r >> 12, n = r & 4095;
    const float* src = (n < NHALF) ? (emb_i + ((size_t)l * NHALF + n) * DDIM)
                                   : (emb_j + ((size_t)l * NHALF + (n - NHALF)) * DDIM);
    float2 v = *(const float2*)(src + lane * 2);
    float ss = v.x * v.x + v.y * v.y;
    #pragma unroll
    for (int off = 1; off < 64; off <<= 1) ss += __shfl_xor(ss, off);
    float inv = SQRT_SCALE / fmaxf(sqrtf(ss), 1e-12f);
    unsigned pack = ((unsigned)f2bf(v.y * inv) << 16) | (unsigned)f2bf(v.x * inv);
    *(unsigned*)(z + (size_t)r * DDIM + lane * 2) = pack;
}

// ---------------- kernel 2: SYMMETRIC sim GEMM + exp2 row/col sums + diag/pos --------------
// Upper-triangle of 32x32 tile grid: idx = J*(J+1)/2 + I, I<=J, 528 tiles per l.
// 128x128 tiles, 32 rows/wave, uncapped VGPR (caps spill: R1/R5/R9), atomics to rowsum
// (R6 showed L2 absorbs them for free). bx&3 = l pins each XCD to one l (z slice 1MB,
// L2-resident).
__global__ __launch_bounds__(256) void k_sim(const unsigned short* __restrict__ z,
                                             float* __restrict__ rowsum,
                                             float* __restrict__ diag,
                                             float* __restrict__ pos) {
    __shared__ __align__(16) unsigned short lds[128 * LDST];
    int bx = blockIdx.x, tid = threadIdx.x;
    int l = bx & 3, idx = bx >> 2;            // idx in [0,528)
    int J = (int)((sqrtf(8.f * (float)idx + 1.f) - 1.f) * 0.5f);
    while ((J + 1) * (J + 2) / 2 <= idx) ++J; // guard fp rounding
    while (J * (J + 1) / 2 > idx) --J;
    int I = idx - J * (J + 1) / 2;
    int wave = tid >> 6, lane = tid & 63, m = lane & 15, quad = lane >> 4;
    const unsigned short* zl = z + (size_t)l * NROWS * DDIM;
    int l4 = l * NROWS;
    int wr0 = I * 128 + wave * 32;            // 32 rows per wave
    int cg0 = J * 128;

    short8 a[2][4];                           // 2 row-subtiles x 4 k-steps
    #pragma unroll
    for (int rs = 0; rs < 2; ++rs) {
        const unsigned short* p = zl + (size_t)(wr0 + rs * 16 + m) * DDIM + quad * 8;
        #pragma unroll
        for (int kk = 0; kk < 4; ++kk) a[rs][kk] = *(const short8*)(p + kk * 32);
    }
    floatx4 rsum[2];
    #pragma unroll
    for (int rs = 0; rs < 2; ++rs) rsum[rs] = (floatx4){0.f, 0.f, 0.f, 0.f};
    float csum[8];                            // per-lane col partial, col = cs*16 + m
    #pragma unroll
    for (int g = 0; g < 8; ++g) csum[g] = 0.f;

    // stage 128x128 bf16 B-tile (cols cg0..cg0+127), 16B chunks, coalesced
    #pragma unroll
    for (int i = 0; i < 8; ++i) {
        int chunk = tid + 256 * i;
        int col = chunk >> 4, off = chunk & 15;
        uint4 d = *(const uint4*)(zl + (size_t)(cg0 + col) * DDIM + off * 8);
        *(uint4*)&lds[col * LDST + off * 8] = d;
    }
    __syncthreads();

    #pragma unroll
    for (int cs = 0; cs < 8; ++cs) {          // 16-col subtiles
        int ct = cg0 + cs * 16;               // tile column base (wave-uniform)
        const unsigned short* lp = &lds[(cs * 16 + m) * LDST + quad * 8];
        short8 b0 = *(const short8*)(lp);
        short8 b1 = *(const short8*)(lp + 32);
        short8 b2 = *(const short8*)(lp + 64);
        short8 b3 = *(const short8*)(lp + 96);
        #pragma unroll
        for (int rs = 0; rs < 2; ++rs) {
            floatx4 acc = (floatx4){0.f, 0.f, 0.f, 0.f};
            acc = __builtin_amdgcn_mfma_f32_16x16x32_bf16(a[rs][0], b0, acc, 0, 0, 0);
            acc = __builtin_amdgcn_mfma_f32_16x16x32_bf16(a[rs][1], b1, acc, 0, 0, 0);
            acc = __builtin_amdgcn_mfma_f32_16x16x32_bf16(a[rs][2], b2, acc, 0, 0, 0);
            acc = __builtin_amdgcn_mfma_f32_16x16x32_bf16(a[rs][3], b3, acc, 0, 0, 0);
            int rowbase = wr0 + rs * 16;
            bool isdiag = (ct == rowbase);          // only when I==J, cs == wave*2+rs
            bool ispos  = (ct == rowbase + 2048);   // only when J==I+16, cs == wave*2+rs
            if (isdiag || ispos) {            // rare, wave-uniform branch
                int c = m - (quad << 2);      // acc[c] holds sim[rowbase+quad*4+c][ct+m]
                if (c >= 0 && c < 4) {        // -> diagonal element iff quad*4+c == m
                    float v = acc[c];
                    if (isdiag) diag[l4 + rowbase + m] = v;
                    else {                    // sim[r, r+2048]; pos symmetric across halves
                        pos[l4 + rowbase + m] = v;
                        pos[l4 + rowbase + m + NHALF] = v;
                    }
                }
            }
            float t = 0.f;
            #pragma unroll
            for (int c = 0; c < 4; ++c) {
                float e = __builtin_amdgcn_exp2f(acc[c]);
                rsum[rs][c] += e;
                t += e;                       // sum over this lane's 4 rows
            }
            csum[cs] += t;                    // accumulate col partial across rs
        }
    }
    // row side: reduce across the 16 column-lanes (bits 0..3 of lane)
    #pragma unroll
    for (int off = 1; off < 16; off <<= 1)
        #pragma unroll
        for (int rs = 0; rs < 2; ++rs)
            #pragma unroll
            for (int c = 0; c < 4; ++c)
                rsum[rs][c] += __shfl_xor(rsum[rs][c], off);
    if (m == 0) {                             // lanes 0,16,32,48: rows wr0 + rs*16 + quad*4 + c
        #pragma unroll
        for (int rs = 0; rs < 2; ++rs)
            #pragma unroll
            for (int c = 0; c < 4; ++c) {
                int rg = wr0 + rs * 16 + quad * 4 + c;
                atomicAdd(&rowsum[l4 + rg], rsum[rs][c]);
            }
    }
    // col side (transpose contribution), off-diagonal tiles only — block-uniform branch
    if (I != J) {
        __syncthreads();                      // LDS tile dead; reuse as float reduce buffer
        float* cred = (float*)lds;            // [4 waves][128 cols]
        #pragma unroll
        for (int g = 0; g < 8; ++g) {         // finish reduce over the 16 rows (lane bits 4,5)
            float v = csum[g];
            v += __shfl_xor(v, 16);
            v += __shfl_xor(v, 32);
            if (quad == 0) cred[wave * 128 + g * 16 + m] = v;
        }
        __syncthreads();
        if (tid < 128) {
            float s = cred[tid] + cred[tid + 128] + cred[tid + 256] + cred[tid + 384];
            atomicAdd(&rowsum[l4 + cg0 + tid], s);  // 128 atomics/block (LDS pre-reduced)
        }
    }
}

// ---------------- kernel 3: per-row loss; last block finishes the scalar -------------------
__global__ __launch_bounds__(256) void k_loss(const float* __restrict__ jv,
                                              const float* __restrict__ rowsum,
                                              const float* __restrict__ diag,
                                              const float* __restrict__ pos,
                                              float* __restrict__ wsf,
                                              float* __restrict__ out) {
    __shared__ float sred[256];
    int tid = threadIdx.x;
    int r = blockIdx.x * 256 + tid;           // 64 blocks x 256 = 16384 rows
    int n = r & 4095;
    float denom = rowsum[r] - __builtin_amdgcn_exp2f(diag[r]);  // exact: same fp32 value
    float contrib = LN2 * (__builtin_amdgcn_logf(denom) - pos[r]); // logf = v_log_f32 = log2
    float local = contrib * jv[n & (NHALF - 1)];
    sred[tid] = local; __syncthreads();
    for (int off = 128; off > 0; off >>= 1) {
        if (tid < off) sred[tid] += sred[tid + off];
        __syncthreads();
    }
    if (tid == 0) {
        atomicAdd(&wsf[0], sred[0]);
        __threadfence();                      // order loss-add before counter-add
        unsigned c = atomicAdd((unsigned*)&wsf[2], 1u);
        if (c == 63) {                        // 64th (last) block: finalize
            float tot = atomicAdd(&wsf[0], 0.f);   // device-scope coherent read
            out[0] = tot / (2.f * wsf[1]);
        }
    }
}

extern "C" void kernel_launch(void* const* d_in, const int* in_sizes, int n_in,
                              void* d_out, int out_size, void* d_ws, size_t ws_size,
                              hipStream_t stream) {
    const float* emb_i = (const float*)d_in[0];
    const float* emb_j = (const float*)d_in[1];
    const float* jv    = (const float*)d_in[2];
    float* wsf    = (float*)d_ws;
    float* rowsum = wsf + WS_ROWSUM_OFF;
    float* diag   = wsf + WS_DIAG_OFF;
    float* pos    = wsf + WS_POS_OFF;
    unsigned short* z = (unsigned short*)((char*)d_ws + WS_Z_BYTE_OFF);
    float* out = (float*)d_out;

    k_norm <<<4097, 256, 0, stream>>>(emb_i, emb_j, jv, wsf, z);
    k_sim  <<<2112, 256, 0, stream>>>(z, rowsum, diag, pos);   // 4 l x 528 upper-tri 128x128
    k_loss <<<64,   256, 0, stream>>>(jv, rowsum, diag, pos, wsf, out);
}